// Round 3
// baseline (483.356 us; speedup 1.0000x reference)
//
#include <hip/hip_runtime.h>

#define DD 300
#define KP 320                      // padded K (10 chunks of 32)
#define NT 19                       // n-tiles of 16 (covers 304)
#define NCH 10                      // k-chunks
#define PLANE_SH 9728               // shorts per W plane-chunk in LDS: 19 tiles * 512
#define WB_SH (2 * PLANE_SH)        // one LDS staging buffer (hi+lo) = 19456 shorts
#define WF_PL 97280                 // shorts per frag-layout W plane: NCH*NT*512
#define SROW_ST 312                 // shorts per s-row: 16B-aligned stride
#define SPLANE_SH (64 * SROW_ST)    // 19968 shorts per s plane (64 rows)

typedef __attribute__((ext_vector_type(8))) short short8;
typedef __attribute__((ext_vector_type(4))) float f32x4;

__device__ __forceinline__ unsigned short bf16_rne(float x) {
    union { float f; unsigned u; } v; v.f = x;
    v.u += 0x7FFF + ((v.u >> 16) & 1);
    return (unsigned short)(v.u >> 16);
}
__device__ __forceinline__ float bf16_to_f32(unsigned short h) {
    union { unsigned u; float f; } v; v.u = (unsigned)h << 16;
    return v.f;
}

// async global->LDS, 16B per lane; LDS dest = wave-uniform base + lane*16
__device__ __forceinline__ void gload_lds16(const void* g, void* l) {
    __builtin_amdgcn_global_load_lds(
        (const __attribute__((address_space(1))) unsigned*)g,
        (__attribute__((address_space(3))) unsigned*)l, 16, 0, 0);
}

// Split Wl into MFMA-fragment-ordered bf16 hi/lo planes:
// Wf[pl][c][t][lane][i] = plane_pl of W[n = t*16 + (lane&15)][k = c*32 + (lane>>4)*8 + i]
// For pl=0 the linear index IS idx; pl=1 at +WF_PL.
__global__ void split_w(const float* __restrict__ Wl, short* __restrict__ Wf) {
    int idx = blockIdx.x * 256 + threadIdx.x;
    if (idx >= WF_PL) return;
    int i = idx & 7, lane = (idx >> 3) & 63, rest = idx >> 9;
    int t = rest % NT, c = rest / NT;
    int n = t * 16 + (lane & 15);
    int k = c * 32 + (lane >> 4) * 8 + i;
    float v = (n < DD && k < DD) ? Wl[n * DD + k] : 0.f;
    unsigned short hi = bf16_rne(v);
    Wf[idx] = (short)hi;
    Wf[idx + WF_PL] = (short)bf16_rne(v - bf16_to_f32(hi));
}

// Fused sub-tree kernel, 8 waves x 16 rows = 128 entry rows per block.
// MODE 0 (kernel A): staged-LDS W at s=0 (8 active waves need LDS BW) with
//   fused level-0 projection; levels s>=1 stream W-frags from L2 (few waves).
// MODE 1 (kernel B): ALL levels stream W-frags from L2 into registers --
//   zero intra-level barriers (3 per level total instead of ~20).
// Inter-level activations: bf16 hi/lo pairsum planes in LDS (bitwise-identical
// values to previous rounds). Tail levels (<16 rows) use one partial tile;
// garbage rows are finite and provably discarded.
template<int MODE, int SLEV>
__global__ __launch_bounds__(512, 1) void tree_fused(
    const float* __restrict__ src, const int* __restrict__ ids,
    const short* __restrict__ Wf,
    const float* __restrict__ bl, const float* __restrict__ Wp,
    const float* __restrict__ bp, float* __restrict__ out,
    float* __restrict__ sdst, int l_entry)
{
    constexpr bool STG = (MODE == 0);
    // A: 77824 B staging dbuf (reused as pj scratch). B: 24576 B pj scratch only.
    __shared__ __align__(16) short wbuf[STG ? 2 * WB_SH : 12288];
    __shared__ __align__(16) short sbuf[2 * SPLANE_SH];   // 79872 B: hi | lo pairsum planes
    const int tid = threadIdx.x;
    const int wid = tid >> 6, lane = tid & 63;
    const int r = lane & 15, q = lane >> 4;
    const int blk = blockIdx.x;

    // zero the k-pad cols [304,312) of both s planes (read by chunk 9, q==2)
    for (int i = tid; i < 64 * 8 * 2; i += 512) {
        int pl = i >> 9, j = i & 511;
        sbuf[pl * SPLANE_SH + (j >> 3) * SROW_ST + 304 + (j & 7)] = 0;
    }

    float pr[2][3] = {};          // MODE0: level-0 projection partials (2 leaves/lane)
    f32x4 acc[NT];

    #pragma unroll 1
    for (int s = 0; s < SLEV; ++s) {
        const int n_l = 128 >> s;                 // valid rows at this level
        const bool actA = (wid * 16) < n_l;
        const int rowA = wid * 16 + r;

        #pragma unroll
        for (int t = 0; t < NT; ++t)
            #pragma unroll
            for (int i = 0; i < 4; ++i) acc[t][i] = 0.f;

        __syncthreads();                          // sbuf from prev epilogue visible; pj scratch free

        if (STG && s == 0) {
            // ---- staged entry level (kernel A): W via LDS double-buffer
            auto stage = [&](int c, int bsel) {
                short* wb = &wbuf[bsel * WB_SH];
                #pragma unroll
                for (int t2i = 0; t2i < 5; ++t2i) {
                    int t2 = wid + t2i * 8;       // wave-uniform piece id
                    if (t2 < 2 * NT) {
                        int pl = t2 >= NT ? 1 : 0;
                        int ss = t2 - pl * NT;
                        gload_lds16(Wf + (long)pl * WF_PL + ((long)c * NT + ss) * 512 + lane * 8,
                                    &wb[pl * PLANE_SH + ss * 512]);
                    }
                }
            };
            stage(0, 0);

            const float *p0, *p1;
            {
                long mA = (long)blk * 128 + rowA;
                p0 = src + (long)ids[2 * mA] * DD;
                p1 = src + (long)ids[2 * mA + 1] * DD;
            }
            f32x4 xc[4], xn[4];
            auto loadx = [&](int c, f32x4* x) {
                int kk = c * 32 + q * 8;
                if (kk + 8 <= DD) {
                    x[0] = *(const f32x4*)(p0 + kk); x[1] = *(const f32x4*)(p0 + kk + 4);
                    x[2] = *(const f32x4*)(p1 + kk); x[3] = *(const f32x4*)(p1 + kk + 4);
                } else {
                    #pragma unroll
                    for (int i = 0; i < 8; ++i) {
                        int kg = kk + i;
                        x[i >> 2][i & 3]       = (kg < DD) ? p0[kg] : 0.f;
                        x[2 + (i >> 2)][i & 3] = (kg < DD) ? p1[kg] : 0.f;
                    }
                }
            };
            loadx(0, xc);
            #pragma unroll 1
            for (int c = 0; c < NCH; ++c) {
                __syncthreads();                  // buf[c&1] staged (vmcnt drained) & visible
                if (c + 1 < NCH) { stage(c + 1, (c + 1) & 1); loadx(c + 1, xn); }
                f32x4 s0v = xc[0] + xc[2], s1v = xc[1] + xc[3];
                short8 xhi, xlo;
                #pragma unroll
                for (int i = 0; i < 4; ++i) {
                    unsigned short h; float v;
                    v = s0v[i]; h = bf16_rne(v); xhi[i]     = (short)h; xlo[i]     = (short)bf16_rne(v - bf16_to_f32(h));
                    v = s1v[i]; h = bf16_rne(v); xhi[4 + i] = (short)h; xlo[4 + i] = (short)bf16_rne(v - bf16_to_f32(h));
                }
                {   // fused level-0 projection partials off the in-register gather
                    int kk = c * 32 + q * 8;
                    #pragma unroll
                    for (int i = 0; i < 8; ++i) {
                        int kg = kk + i;
                        float w0 = (kg < DD) ? Wp[kg] : 0.f;
                        float w1 = (kg < DD) ? Wp[DD + kg] : 0.f;
                        float w2 = (kg < DD) ? Wp[2 * DD + kg] : 0.f;
                        float xa = xc[i >> 2][i & 3];
                        float xb = xc[2 + (i >> 2)][i & 3];
                        pr[0][0] += xa * w0; pr[0][1] += xa * w1; pr[0][2] += xa * w2;
                        pr[1][0] += xb * w0; pr[1][1] += xb * w1; pr[1][2] += xb * w2;
                    }
                }
                const short8* bb = (const short8*)&wbuf[(c & 1) * WB_SH] + lane;
                #pragma unroll
                for (int t = 0; t < NT; ++t) {
                    short8 bh = bb[t * 64];
                    short8 bo = bb[1216 + t * 64];   // + PLANE_SH/8
                    acc[t] = __builtin_amdgcn_mfma_f32_16x16x32_bf16(xhi, bh, acc[t], 0, 0, 0);
                    acc[t] = __builtin_amdgcn_mfma_f32_16x16x32_bf16(xhi, bo, acc[t], 0, 0, 0);
                    acc[t] = __builtin_amdgcn_mfma_f32_16x16x32_bf16(xlo, bh, acc[t], 0, 0, 0);
                }
                if (c + 1 < NCH) {
                    #pragma unroll
                    for (int i = 0; i < 4; ++i) xc[i] = xn[i];
                }
            }
        } else if (s == 0) {
            // ---- stream entry level (kernel B): x rows from global, W from L2
            const float* p0 = src + ((long)blk * 128 + rowA) * DD;
            f32x4 xc[2], xn[2];
            auto loadx = [&](int c, f32x4* x) {
                int kk = c * 32 + q * 8;
                if (kk + 8 <= DD) {
                    x[0] = *(const f32x4*)(p0 + kk); x[1] = *(const f32x4*)(p0 + kk + 4);
                } else {
                    #pragma unroll
                    for (int i = 0; i < 8; ++i) {
                        int kg = kk + i;
                        x[i >> 2][i & 3] = (kg < DD) ? p0[kg] : 0.f;
                    }
                }
            };
            loadx(0, xc);
            #pragma unroll 1
            for (int c = 0; c < NCH; ++c) {
                if (c + 1 < NCH) loadx(c + 1, xn);
                short8 xhi, xlo;
                #pragma unroll
                for (int i = 0; i < 4; ++i) {
                    unsigned short h; float v;
                    v = xc[0][i]; h = bf16_rne(v); xhi[i]     = (short)h; xlo[i]     = (short)bf16_rne(v - bf16_to_f32(h));
                    v = xc[1][i]; h = bf16_rne(v); xhi[4 + i] = (short)h; xlo[4 + i] = (short)bf16_rne(v - bf16_to_f32(h));
                }
                const short8* wfp = (const short8*)Wf + (long)c * NT * 64 + lane;
                #pragma unroll
                for (int t = 0; t < NT; ++t) {
                    short8 bh = wfp[t * 64];
                    short8 bo = wfp[12160 + t * 64];   // + WF_PL/8
                    acc[t] = __builtin_amdgcn_mfma_f32_16x16x32_bf16(xhi, bh, acc[t], 0, 0, 0);
                    acc[t] = __builtin_amdgcn_mfma_f32_16x16x32_bf16(xhi, bo, acc[t], 0, 0, 0);
                    acc[t] = __builtin_amdgcn_mfma_f32_16x16x32_bf16(xlo, bh, acc[t], 0, 0, 0);
                }
                xc[0] = xn[0]; xc[1] = xn[1];
            }
        } else {
            // ---- stream LDS levels: x from pairsum planes, W from L2, no barriers
            if (actA) {
                #pragma unroll 1
                for (int c = 0; c < NCH; ++c) {
                    int kk = c * 32 + q * 8;
                    short8 xhi = {0,0,0,0,0,0,0,0}, xlo = xhi;
                    if (kk + 8 <= SROW_ST) {
                        xhi = *(const short8*)&sbuf[rowA * SROW_ST + kk];
                        xlo = *(const short8*)&sbuf[SPLANE_SH + rowA * SROW_ST + kk];
                    }
                    const short8* wfp = (const short8*)Wf + (long)c * NT * 64 + lane;
                    #pragma unroll
                    for (int t = 0; t < NT; ++t) {
                        short8 bh = wfp[t * 64];
                        short8 bo = wfp[12160 + t * 64];
                        acc[t] = __builtin_amdgcn_mfma_f32_16x16x32_bf16(xhi, bh, acc[t], 0, 0, 0);
                        acc[t] = __builtin_amdgcn_mfma_f32_16x16x32_bf16(xhi, bo, acc[t], 0, 0, 0);
                        acc[t] = __builtin_amdgcn_mfma_f32_16x16x32_bf16(xlo, bh, acc[t], 0, 0, 0);
                    }
                }
            }
        }

        // ---- epilogue: bias + ReLU, pairsum -> sbuf (or seam global), pj partials
        __syncthreads();                          // all waves done reading wbuf & sbuf
        float* pjb = (float*)wbuf;                // [row128][r16][3] f32 scratch (24576 B)
        if (actA) {
            float pj[4][3] = {};
            #pragma unroll
            for (int t = 0; t < NT; ++t) {
                int n = t * 16 + r;
                bool nok = n < DD;
                float w0 = nok ? Wp[n] : 0.f;
                float w1 = nok ? Wp[DD + n] : 0.f;
                float w2 = nok ? Wp[2 * DD + n] : 0.f;
                float b2 = nok ? 2.f * bl[n] : 0.f;
                float v[4];
                #pragma unroll
                for (int g = 0; g < 4; ++g) {
                    float a = acc[t][g] + b2; v[g] = a > 0.f ? a : 0.f;
                    pj[g][0] += v[g] * w0; pj[g][1] += v[g] * w1; pj[g][2] += v[g] * w2;
                }
                if (s + 1 < SLEV) {
                    // n in [300,304) gets exact 0 (W pad) -> safe unguarded write
                    int sr = wid * 8 + q * 2;
                    float sa = v[0] + v[1], sb = v[2] + v[3];
                    unsigned short h;
                    h = bf16_rne(sa);
                    sbuf[sr * SROW_ST + n] = (short)h;
                    sbuf[SPLANE_SH + sr * SROW_ST + n] = (short)bf16_rne(sa - bf16_to_f32(h));
                    h = bf16_rne(sb);
                    sbuf[(sr + 1) * SROW_ST + n] = (short)h;
                    sbuf[SPLANE_SH + (sr + 1) * SROW_ST + n] = (short)bf16_rne(sb - bf16_to_f32(h));
                } else if (sdst != nullptr) {
                    if (nok) {
                        int sr = blk * 8 + q * 2;
                        sdst[(size_t)sr * DD + n]       = v[0] + v[1];
                        sdst[(size_t)(sr + 1) * DD + n] = v[2] + v[3];
                    }
                }
            }
            #pragma unroll
            for (int g = 0; g < 4; ++g)
                #pragma unroll
                for (int cc = 0; cc < 3; ++cc)
                    pjb[((wid * 16 + q * 4 + g) * 16 + r) * 3 + cc] = pj[g][cc];
        }
        __syncthreads();
        if (tid < n_l) {
            const float* base = &pjb[tid * 48];
            float o0 = 0.f, o1 = 0.f, o2 = 0.f;
            #pragma unroll
            for (int rr = 0; rr < 16; ++rr) {
                o0 += base[rr * 3]; o1 += base[rr * 3 + 1]; o2 += base[rr * 3 + 2];
            }
            int la = l_entry + s;
            int lg = 12 - la;
            int offk = 8192 - (8192 >> la);
            int g_row = blk * n_l + tid;
            int b = g_row >> lg, n2 = g_row & ((1 << lg) - 1);
            float* o = out + ((size_t)b * 8191 + offk + n2) * 3;
            o[0] = o0 + bp[0]; o[1] = o1 + bp[1]; o[2] = o2 + bp[2];
        }

        if (MODE == 0 && s == 0) {
            // level-0 projection: reduce pr over the 4 q-groups, 256 leaves/block
            #pragma unroll
            for (int j = 0; j < 2; ++j)
                #pragma unroll
                for (int cc = 0; cc < 3; ++cc) {
                    float v = pr[j][cc];
                    v += __shfl_xor(v, 16);
                    v += __shfl_xor(v, 32);
                    pr[j][cc] = v;
                }
            if (q == 0) {
                long mA = (long)blk * 128 + wid * 16 + r;
                #pragma unroll
                for (int j = 0; j < 2; ++j) {
                    long gr = 2 * mA + j;
                    int b = (int)(gr >> 12), n = (int)(gr & 4095);
                    float* o = out + ((size_t)b * 8191 + n) * 3;
                    o[0] = pr[j][0] + bp[0];
                    o[1] = pr[j][1] + bp[1];
                    o[2] = pr[j][2] + bp[2];
                }
            }
        }
    }
}

extern "C" void kernel_launch(void* const* d_in, const int* in_sizes, int n_in,
                              void* d_out, int out_size, void* d_ws, size_t ws_size,
                              hipStream_t stream)
{
    const int*   word_ids  = (const int*)d_in[0];    // (32, 4096) int32
    const float* embedding = (const float*)d_in[1];  // (50000, 300) f32
    const float* Wl        = (const float*)d_in[2];  // (300, 300) f32
    const float* bl        = (const float*)d_in[3];  // (300,) f32
    const float* Wp        = (const float*)d_in[4];  // (3, 300) f32
    const float* bp        = (const float*)d_in[5];  // (3,) f32
    float* out = (float*)d_out;

    // ws: Wf (2 planes x 97280 shorts = 389120 B) | s4 (4096x300 f32)
    char* ws = (char*)d_ws;
    short* Wf = (short*)ws;
    float* s4 = (float*)(ws + 2 * WF_PL * 2);

    split_w<<<(WF_PL + 255) / 256, 256, 0, stream>>>(Wl, Wf);

    // A: level-0 proj + levels 1..4 (65536 L1 rows, 128/block, 8 waves)
    tree_fused<0, 4><<<512, 512, 0, stream>>>(embedding, word_ids, Wf, bl, Wp, bp, out, s4, 1);
    // B: levels 5..12 (each block owns one batch's full subtree: 128 -> 1 rows)
    tree_fused<1, 8><<<32, 512, 0, stream>>>(s4, nullptr, Wf, bl, Wp, bp, out, nullptr, 5);
}